// Round 10
// baseline (3959.552 us; speedup 1.0000x reference)
//
#include <hip/hip_runtime.h>
#include <cstdint>
#include <cstddef>

#define V_SZ 32000
#define H_SZ 1024
#define T_SZ 512
#define B_SZ 64

typedef short short8 __attribute__((ext_vector_type(8)));
typedef float f32x4 __attribute__((ext_vector_type(4)));
typedef unsigned long long u64;

__device__ __forceinline__ short f2bf(float f) {
  union { float f; unsigned u; } v; v.f = f;
  unsigned r = (v.u + 0x7fffu + ((v.u >> 16) & 1u)) >> 16;  // RNE, inputs finite
  return (short)r;
}

__device__ __forceinline__ unsigned cvtpk(float a, float b) {  // {bf16(a),bf16(b)}
  unsigned r;
  asm("v_cvt_pk_bf16_f32 %0, %1, %2" : "=v"(r) : "v"(a), "v"(b));
  return r;
}

__device__ __forceinline__ float fsig(float x) {   // 1/(1+e^-x) via v_exp/v_rcp
  return __builtin_amdgcn_rcpf(1.f + __builtin_amdgcn_exp2f(x * -1.44269504f));
}
__device__ __forceinline__ float ftanh(float x) {  // 1 - 2/(e^2x+1)
  return 1.f - 2.f * __builtin_amdgcn_rcpf(1.f + __builtin_amdgcn_exp2f(x * 2.88539008f));
}

// embT[v][h] = bf16(emb_w[h][v] + emb_b[h])  -- tiled transpose, both sides coalesced
__global__ __launch_bounds__(256) void k_embT(const float* __restrict__ emb_w,
                                              const float* __restrict__ emb_b,
                                              short* __restrict__ embT) {
  __shared__ float tile[64][65];
  const int v0 = blockIdx.x * 64, h0 = blockIdx.y * 64;
  const int c = threadIdx.x & 63, rg = threadIdx.x >> 6;
#pragma unroll
  for (int p = 0; p < 16; ++p) {
    int r = rg * 16 + p;
    tile[r][c] = emb_w[(size_t)(h0 + r) * V_SZ + v0 + c];
  }
  __syncthreads();
  const float bias = emb_b[h0 + c];
#pragma unroll
  for (int p = 0; p < 16; ++p) {
    int vr = rg * 16 + p;
    embT[(size_t)(v0 + vr) * H_SZ + h0 + c] = f2bf(tile[c][vr] + bias);
  }
}

__global__ __launch_bounds__(256) void k_cast(const float* __restrict__ s,
                                              short* __restrict__ d, int n) {
  for (int i = blockIdx.x * 256 + threadIdx.x; i < n; i += gridDim.x * 256)
    d[i] = f2bf(s[i]);
}

__global__ __launch_bounds__(256) void k_copy(const float* __restrict__ s,
                                              float* __restrict__ d, int n) {
  for (int i = blockIdx.x * 256 + threadIdx.x; i < n; i += gridDim.x * 256)
    d[i] = s[i];
}

// Persistent bidirectional LSTM. 256 blocks x 512 threads, 1 block/CU.
// h-exchange THROUGH out[] (write-once addresses): producers publish hidden as
// UC write-through f32 (sc0 sc1 -> L3 at vmcnt-retire); consumers read out[t-1]
// with PLAIN CACHED loads (monotone addresses can't be stale; entry fence kills
// poison lines) -> 64x read reuse now served by XCD L2 instead of the fabric.
// Role map: m8=bid%8 (default round-robin XCD): d=m8>>2, bg=(m8>>1)&1,
// cg=(m8&1)*32+bid/8 -> blocks sharing h rows cluster on XCD pairs.
// Weights (Bf[8][4]=128 regs) in registers all 512 steps; c-state in register.
// t=0: h==0 -> skip h-half entirely. Fast gates via v_exp_f32/v_rcp_f32.
__global__ __launch_bounds__(512, 2) void k_persist(
    const int* __restrict__ tokens, const short* __restrict__ embT,
    const short* __restrict__ Wbf, const float* __restrict__ biasws,
    unsigned* __restrict__ bar, float* __restrict__ out) {
  __shared__ float P_lds[8][32][68];   // [K-eighth][b32][64 cols + 4 pad]

  const int tid = threadIdx.x;
  const int lane = tid & 63, w = tid >> 6;
  const int l15 = lane & 15, l4 = lane >> 4;
  const int bid = (int)blockIdx.x;
  const int m8 = bid & 7;
  const int d = m8 >> 2;                     // direction
  const int bg = (m8 >> 1) & 1;              // batch half
  const int cg = (m8 & 1) * 32 + (bid >> 3); // col group 0..63
  const int n0 = cg << 4;
  const int r0 = bg * 32 + l15, r1 = r0 + 16;  // A-fragment batch rows
  const int kw = w * 32 + l4 * 8;              // lane k-base (slab w, quarter l4)

  __threadfence();  // one-time wb+inv: drop poison/memset lines before cached h reads

  // ---- step-invariant B fragments in registers: slab w+jj*8, N-tile nt ----
  short8 Bf[8][4];
#pragma unroll
  for (int jj = 0; jj < 8; ++jj) {
    int slab = w + jj * 8;
#pragma unroll
    for (int nt = 0; nt < 4; ++nt) {
      int row64 = nt * 16 + l15;             // flat (gate,col) 0..63
      size_t grow = (size_t)((d * 4 + (row64 >> 4)) * 1024 + n0 + (row64 & 15));
      Bf[jj][nt] = *(const short8*)(Wbf + grow * 2048 + slab * 32 + l4 * 8);
    }
  }

  // ---- gate-phase constants: thread owns (b32=tid>>4, c16=tid&15) ----
  const int b32 = tid >> 4, c16 = tid & 15;
  const int gcol = n0 + c16, gbrow = bg * 32 + b32;
  float brg[4];
#pragma unroll
  for (int g4 = 0; g4 < 4; ++g4) brg[g4] = biasws[d * 4096 + g4 * 1024 + gcol];
  float c_reg = 0.f;

  // ---- single hierarchical barrier: 16 groups x 16 blocks + root ----
  unsigned* const grpc = bar + 16 + (bid >> 4) * 16;
  unsigned* const root = bar;

  const f32x4 fzero = {0.f, 0.f, 0.f, 0.f};
  f32x4 acc[2][4];

  // x-half of step s (token-dependent only): cached direct-to-frag + 32 MFMA.
  auto X_PHASE = [&](int s) {
    const int td = d ? (T_SZ - 1 - s) : s;
    const short* xb0 = embT + (size_t)tokens[td * B_SZ + r0] * 1024 + kw;
    const short* xb1 = embT + (size_t)tokens[td * B_SZ + r1] * 1024 + kw;
    short8 xf[2][4];
#pragma unroll
    for (int jj = 0; jj < 4; ++jj) {         // slab w+jj*8 -> +jj*256 elements
      xf[0][jj] = *(const short8*)(xb0 + jj * 256);
      xf[1][jj] = *(const short8*)(xb1 + jj * 256);
    }
#pragma unroll
    for (int ms = 0; ms < 2; ++ms)
#pragma unroll
      for (int nt = 0; nt < 4; ++nt) acc[ms][nt] = fzero;
#pragma unroll
    for (int jj = 0; jj < 4; ++jj)
#pragma unroll
      for (int ms = 0; ms < 2; ++ms)
#pragma unroll
        for (int nt = 0; nt < 4; ++nt)
          acc[ms][nt] = __builtin_amdgcn_mfma_f32_16x16x32_bf16(
              xf[ms][jj], Bf[jj][nt], acc[ms][nt], 0, 0, 0);
  };

  X_PHASE(0);  // prologue

  for (int t = 0; t < T_SZ; ++t) {
    // ---- h-half: CACHED f32 reads of out[t-1] hidden + cvt_pk -> bf16 frags ----
    if (t > 0) {
      const float* hb0 = out + ((size_t)(t - 1) * B_SZ + r0) * 2048 + (size_t)d * 1024 + kw;
      const float* hb1 = out + ((size_t)(t - 1) * B_SZ + r1) * 2048 + (size_t)d * 1024 + kw;
      short8 hf[2][4];
#pragma unroll
      for (int q = 0; q < 4; ++q) {          // h-slab q -> k offset q*256
        f32x4 a0 = *(const f32x4*)(hb0 + q * 256);
        f32x4 a1 = *(const f32x4*)(hb0 + q * 256 + 4);
        f32x4 b0 = *(const f32x4*)(hb1 + q * 256);
        f32x4 b1 = *(const f32x4*)(hb1 + q * 256 + 4);
        union { unsigned u[4]; short8 s; } c0, c1;
        c0.u[0] = cvtpk(a0[0], a0[1]); c0.u[1] = cvtpk(a0[2], a0[3]);
        c0.u[2] = cvtpk(a1[0], a1[1]); c0.u[3] = cvtpk(a1[2], a1[3]);
        c1.u[0] = cvtpk(b0[0], b0[1]); c1.u[1] = cvtpk(b0[2], b0[3]);
        c1.u[2] = cvtpk(b1[0], b1[1]); c1.u[3] = cvtpk(b1[2], b1[3]);
        hf[0][q] = c0.s; hf[1][q] = c1.s;
      }
#pragma unroll
      for (int q = 0; q < 4; ++q)
#pragma unroll
        for (int ms = 0; ms < 2; ++ms)
#pragma unroll
          for (int nt = 0; nt < 4; ++nt)
            acc[ms][nt] = __builtin_amdgcn_mfma_f32_16x16x32_bf16(
                hf[ms][q], Bf[4 + q][nt], acc[ms][nt], 0, 0, 0);
    }

    // ---- K-split partial dump (C layout: row=l4*4+i, col=l15) ----
#pragma unroll
    for (int ms = 0; ms < 2; ++ms)
#pragma unroll
      for (int nt = 0; nt < 4; ++nt)
#pragma unroll
        for (int i = 0; i < 4; ++i)
          P_lds[w][ms * 16 + l4 * 4 + i][nt * 16 + l15] = acc[ms][nt][i];
    __syncthreads();

    // ---- gate math + state update (thread: b32, c16) ----
    float pr[4];
#pragma unroll
    for (int g4 = 0; g4 < 4; ++g4) {
      float s = brg[g4];
#pragma unroll
      for (int q = 0; q < 8; ++q) s += P_lds[q][b32][g4 * 16 + c16];
      pr[g4] = s;
    }
    float ig = fsig(pr[0]);
    float og = fsig(pr[1]);
    float fg = fsig(pr[2]);
    float cg4 = ftanh(pr[3]);
    c_reg = fg * c_reg + ig * cg4;
    float hnew = og * ftanh(c_reg);

    // ---- publish hidden: shuffle-pack 4 lanes -> one 16B UC write-through ----
    {
      float s1 = __shfl_down(hnew, 1);
      float s2 = __shfl_down(hnew, 2);
      float s3 = __shfl_down(hnew, 3);
      if ((lane & 3) == 0) {
        f32x4 pk = {hnew, s1, s2, s3};
        float* p = out + ((size_t)t * B_SZ + bg * 32 + (w * 4 + (lane >> 4))) * 2048 +
                   (size_t)d * 1024 + n0 + (lane & 15);
        asm volatile("global_store_dwordx4 %0, %1, off sc0 sc1"
                     :: "v"(p), "v"(pk) : "memory");
      }
    }

    if (t < T_SZ - 1) {
      __syncthreads();   // each wave's vmcnt(0) drains its UC publishes -> in L3
      if (tid == 0) {    // arrive: group counter, last-of-group bumps root
        unsigned old = __hip_atomic_fetch_add(grpc, 1u, __ATOMIC_RELAXED,
                                              __HIP_MEMORY_SCOPE_AGENT);
        if (old == (unsigned)((t + 1) * 16 - 1))
          __hip_atomic_fetch_add(root, 1u, __ATOMIC_RELAXED,
                                 __HIP_MEMORY_SCOPE_AGENT);
      }
      // overlap region: cell store (cached) + next step's x-half
      out[((size_t)t * B_SZ + gbrow) * 2048 + (size_t)d * 1024 + gcol + 67108864] = c_reg;
      X_PHASE(t + 1);
      if (tid == 0) {
        const unsigned tgt = (unsigned)((t + 1) * 16);  // 16 groups
        while (__hip_atomic_load(root, __ATOMIC_RELAXED,
                                 __HIP_MEMORY_SCOPE_AGENT) < tgt)
          __builtin_amdgcn_s_sleep(2);
      }
      __syncthreads();
    } else {
      out[((size_t)t * B_SZ + gbrow) * 2048 + (size_t)d * 1024 + gcol + 67108864] = c_reg;
    }
  }
}

extern "C" void kernel_launch(void* const* d_in, const int* in_sizes, int n_in,
                              void* d_out, int out_size, void* d_ws, size_t ws_size,
                              hipStream_t stream) {
  (void)in_sizes; (void)n_in; (void)out_size; (void)ws_size;
  const int* tokens  = (const int*)d_in[0];
  const float* emb_w = (const float*)d_in[1];
  const float* emb_b = (const float*)d_in[2];

  char* ws = (char*)d_ws;
  short* embT   = (short*)(ws);               // 65,536,000 B
  short* Wbf    = (short*)(ws + 65536000);    // 33,554,432 B
  float* biasws = (float*)(ws + 99090432);    //     32,768 B
  unsigned* bar = (unsigned*)(ws + 99123200); //      2,048 B

  (void)hipMemsetAsync(ws + 99123200, 0, 2048, stream);

  k_embT<<<dim3(500, 16), 256, 0, stream>>>(emb_w, emb_b, embT);

  for (int d = 0; d < 2; ++d)
    for (int g = 0; g < 4; ++g) {
      const float* wsrc = (const float*)d_in[3 + d * 8 + g * 2];
      const float* bsrc = (const float*)d_in[4 + d * 8 + g * 2];
      k_cast<<<1024, 256, 0, stream>>>(wsrc, Wbf + (size_t)(d * 4 + g) * 1024 * 2048,
                                       1024 * 2048);
      k_copy<<<4, 256, 0, stream>>>(bsrc, biasws + (d * 4 + g) * 1024, 1024);
    }

  float* outp = (float*)d_out;
  void* kargs[] = {(void*)&tokens, (void*)&embT, (void*)&Wbf, (void*)&biasws,
                   (void*)&bar, (void*)&outp};
  (void)hipLaunchCooperativeKernel((const void*)k_persist, dim3(256), dim3(512), kargs,
                                   0, stream);
}

// Round 11
// 3100.904 us; speedup vs baseline: 1.2769x; 1.2769x over previous
//
#include <hip/hip_runtime.h>
#include <cstdint>
#include <cstddef>

#define V_SZ 32000
#define H_SZ 1024
#define T_SZ 512
#define B_SZ 64

typedef short short8 __attribute__((ext_vector_type(8)));
typedef float f32x4 __attribute__((ext_vector_type(4)));
typedef unsigned long long u64;

__device__ __forceinline__ short f2bf(float f) {
  union { float f; unsigned u; } v; v.f = f;
  unsigned r = (v.u + 0x7fffu + ((v.u >> 16) & 1u)) >> 16;  // RNE, inputs finite
  return (short)r;
}

__device__ __forceinline__ void cs8(u64* p, u64 v) {
  __hip_atomic_store(p, v, __ATOMIC_RELAXED, __HIP_MEMORY_SCOPE_AGENT);
}

__device__ __forceinline__ float fsig(float x) {   // 1/(1+e^-x) via v_exp/v_rcp
  return __builtin_amdgcn_rcpf(1.f + __builtin_amdgcn_exp2f(x * -1.44269504f));
}
__device__ __forceinline__ float ftanh(float x) {  // 1 - 2/(e^2x+1)
  return 1.f - 2.f * __builtin_amdgcn_rcpf(1.f + __builtin_amdgcn_exp2f(x * 2.88539008f));
}

// embT[v][h] = bf16(emb_w[h][v] + emb_b[h])  -- tiled transpose, both sides coalesced
__global__ __launch_bounds__(256) void k_embT(const float* __restrict__ emb_w,
                                              const float* __restrict__ emb_b,
                                              short* __restrict__ embT) {
  __shared__ float tile[64][65];
  const int v0 = blockIdx.x * 64, h0 = blockIdx.y * 64;
  const int c = threadIdx.x & 63, rg = threadIdx.x >> 6;
#pragma unroll
  for (int p = 0; p < 16; ++p) {
    int r = rg * 16 + p;
    tile[r][c] = emb_w[(size_t)(h0 + r) * V_SZ + v0 + c];
  }
  __syncthreads();
  const float bias = emb_b[h0 + c];
#pragma unroll
  for (int p = 0; p < 16; ++p) {
    int vr = rg * 16 + p;
    embT[(size_t)(v0 + vr) * H_SZ + h0 + c] = f2bf(tile[c][vr] + bias);
  }
}

__global__ __launch_bounds__(256) void k_cast(const float* __restrict__ s,
                                              short* __restrict__ d, int n) {
  for (int i = blockIdx.x * 256 + threadIdx.x; i < n; i += gridDim.x * 256)
    d[i] = f2bf(s[i]);
}

__global__ __launch_bounds__(256) void k_copy(const float* __restrict__ s,
                                              float* __restrict__ d, int n) {
  for (int i = blockIdx.x * 256 + threadIdx.x; i < n; i += gridDim.x * 256)
    d[i] = s[i];
}

// Persistent bidirectional LSTM. 256 blocks x 512 threads, 1 block/CU.
// block: d = bid>>7, bg = (bid&127)>>6 (batch half), cg = bid&63, n0 = cg*16.
// wave w owns K-slabs {j : j%8==w} (4 x-slabs + 4 h-slabs).
// Weights (Bf[8][4]=128 regs) in registers all 512 steps; c-state in register.
// h-exchange: 2-phase UC bf16 buffer (16B asm loads / repacked 8B stores).
// Sync: DATAFLOW FLAGS per (d,bg) group of 64 blocks -- producer sets
// flag[d][bg][cg]=t+1 (UC store, monotone); consumer wave0's 64 lanes poll all
// 64 group flags (ballot). No RMW tree, no cross-group coupling. Poll overlapped
// behind next step's x-half MFMA + out[] stores.
__global__ __launch_bounds__(512, 2) void k_persist(
    const int* __restrict__ tokens, const short* __restrict__ embT,
    const short* __restrict__ Wbf, const float* __restrict__ biasws,
    short* __restrict__ hbf, unsigned* __restrict__ bar,
    float* __restrict__ out) {
  __shared__ float P_lds[8][32][68];   // [K-eighth][b32][64 cols + 4 pad]
  __shared__ short h_sh[32][16];       // publish repack buffer

  const int tid = threadIdx.x;
  const int lane = tid & 63, w = tid >> 6;
  const int l15 = lane & 15, l4 = lane >> 4;
  const int d = (int)(blockIdx.x >> 7);
  const int bflat = (int)(blockIdx.x & 127);
  const int bg = bflat >> 6;                 // 0..1 batch half
  const int cg = bflat & 63;                 // 0..63 col group
  const int n0 = cg << 4;
  const int r0 = bg * 32 + l15, r1 = r0 + 16;  // A-fragment batch rows
  const int kw = w * 32 + l4 * 8;              // lane k-base (slab w, quarter l4)

  // ---- step-invariant B fragments in registers: slab w+jj*8, N-tile nt ----
  short8 Bf[8][4];
#pragma unroll
  for (int jj = 0; jj < 8; ++jj) {
    int slab = w + jj * 8;
#pragma unroll
    for (int nt = 0; nt < 4; ++nt) {
      int row64 = nt * 16 + l15;             // flat (gate,col) 0..63
      size_t grow = (size_t)((d * 4 + (row64 >> 4)) * 1024 + n0 + (row64 & 15));
      Bf[jj][nt] = *(const short8*)(Wbf + grow * 2048 + slab * 32 + l4 * 8);
    }
  }

  // ---- gate-phase constants: thread owns (b32=tid>>4, c16=tid&15) ----
  const int b32 = tid >> 4, c16 = tid & 15;
  const int gcol = n0 + c16, gbrow = bg * 32 + b32;
  float brg[4];
#pragma unroll
  for (int g4 = 0; g4 < 4; ++g4) brg[g4] = biasws[d * 4096 + g4 * 1024 + gcol];
  float c_reg = 0.f;

  // ---- dataflow flags: u32 [d][bg][cg]; monotone values, no reset ----
  unsigned* const gflags = bar + (d * 2 + bg) * 64;   // this group's 64 flags

  const f32x4 fzero = {0.f, 0.f, 0.f, 0.f};
  f32x4 acc[2][4];

  // x-half of step s (token-dependent only): cached direct-to-frag + 32 MFMA.
  auto X_PHASE = [&](int s) {
    const int td = d ? (T_SZ - 1 - s) : s;
    const short* xb0 = embT + (size_t)tokens[td * B_SZ + r0] * 1024 + kw;
    const short* xb1 = embT + (size_t)tokens[td * B_SZ + r1] * 1024 + kw;
    short8 xf[2][4];
#pragma unroll
    for (int jj = 0; jj < 4; ++jj) {         // slab w+jj*8 -> +jj*256 elements
      xf[0][jj] = *(const short8*)(xb0 + jj * 256);
      xf[1][jj] = *(const short8*)(xb1 + jj * 256);
    }
#pragma unroll
    for (int ms = 0; ms < 2; ++ms)
#pragma unroll
      for (int nt = 0; nt < 4; ++nt) acc[ms][nt] = fzero;
#pragma unroll
    for (int jj = 0; jj < 4; ++jj)
#pragma unroll
      for (int ms = 0; ms < 2; ++ms)
#pragma unroll
        for (int nt = 0; nt < 4; ++nt)
          acc[ms][nt] = __builtin_amdgcn_mfma_f32_16x16x32_bf16(
              xf[ms][jj], Bf[jj][nt], acc[ms][nt], 0, 0, 0);
  };

  X_PHASE(0);  // prologue

  for (int t = 0; t < T_SZ; ++t) {
    // ---- h-half: UC 16B fragment loads (early-clobber asm blob) + 32 MFMA ----
    if (t > 0) {
      const short* hsrc = hbf + ((t & 1) * 2 + d) * 65536;
      const short* hb0 = hsrc + r0 * 1024 + kw;
      const short* hb1 = hsrc + r1 * 1024 + kw;
      short8 hf[2][4];
      asm volatile(
          "global_load_dwordx4 %0, %8, off sc0 sc1\n\t"
          "global_load_dwordx4 %1, %8, off offset:512 sc0 sc1\n\t"
          "global_load_dwordx4 %2, %8, off offset:1024 sc0 sc1\n\t"
          "global_load_dwordx4 %3, %8, off offset:1536 sc0 sc1\n\t"
          "global_load_dwordx4 %4, %9, off sc0 sc1\n\t"
          "global_load_dwordx4 %5, %9, off offset:512 sc0 sc1\n\t"
          "global_load_dwordx4 %6, %9, off offset:1024 sc0 sc1\n\t"
          "global_load_dwordx4 %7, %9, off offset:1536 sc0 sc1\n\t"
          "s_waitcnt vmcnt(0)"
          : "=&v"(hf[0][0]), "=&v"(hf[0][1]), "=&v"(hf[0][2]), "=&v"(hf[0][3]),
            "=&v"(hf[1][0]), "=&v"(hf[1][1]), "=&v"(hf[1][2]), "=&v"(hf[1][3])
          : "v"(hb0), "v"(hb1)
          : "memory");
#pragma unroll
      for (int q = 0; q < 4; ++q)
#pragma unroll
        for (int ms = 0; ms < 2; ++ms)
#pragma unroll
          for (int nt = 0; nt < 4; ++nt)
            acc[ms][nt] = __builtin_amdgcn_mfma_f32_16x16x32_bf16(
                hf[ms][q], Bf[4 + q][nt], acc[ms][nt], 0, 0, 0);
    }

    // ---- K-split partial dump (C layout: row=l4*4+i, col=l15) ----
#pragma unroll
    for (int ms = 0; ms < 2; ++ms)
#pragma unroll
      for (int nt = 0; nt < 4; ++nt)
#pragma unroll
        for (int i = 0; i < 4; ++i)
          P_lds[w][ms * 16 + l4 * 4 + i][nt * 16 + l15] = acc[ms][nt][i];
    __syncthreads();

    // ---- gate math + state update (thread: b32, c16) ----
    float pr[4];
#pragma unroll
    for (int g4 = 0; g4 < 4; ++g4) {
      float s = brg[g4];
#pragma unroll
      for (int q = 0; q < 8; ++q) s += P_lds[q][b32][g4 * 16 + c16];
      pr[g4] = s;
    }
    float ig = fsig(pr[0]);
    float og = fsig(pr[1]);
    float fg = fsig(pr[2]);
    float cg4 = ftanh(pr[3]);
    c_reg = fg * c_reg + ig * cg4;
    float hnew = og * ftanh(c_reg);

    if (t < T_SZ - 1) {
      // ---- publish: LDS repack -> 128 x 8B UC stores -> drain -> flag ----
      short* hdst = hbf + (((t + 1) & 1) * 2 + d) * 65536;
      h_sh[b32][c16] = f2bf(hnew);
      __syncthreads();                       // h_sh visible
      if (tid < 128) {
        int r = tid >> 2, qq = tid & 3;
        cs8((u64*)(hdst + (bg * 32 + r) * 1024 + n0 + qq * 4),
            *(const u64*)&h_sh[r][qq * 4]);
      }
      __syncthreads();                       // publish drained (per-wave vmcnt 0)
      if (tid == 0)                          // arrive: one UC store, no RMW
        __hip_atomic_store(gflags + cg, (unsigned)(t + 1), __ATOMIC_RELAXED,
                           __HIP_MEMORY_SCOPE_AGENT);

      // overlap region: out[] stores + next step's x-half hide poll latency
      size_t o = (size_t)(t * B_SZ + gbrow) * 2048 + (size_t)d * 1024 + gcol;
      out[o] = hnew;
      out[o + 67108864] = c_reg;
      X_PHASE(t + 1);

      if (w == 0) {                          // wave0: lane i polls group flag i
        const unsigned tgt = (unsigned)(t + 1);
        while (true) {
          unsigned v = __hip_atomic_load(gflags + lane, __ATOMIC_RELAXED,
                                         __HIP_MEMORY_SCOPE_AGENT);
          if (__all(v >= tgt)) break;
          __builtin_amdgcn_s_sleep(1);
        }
      }
      __syncthreads();
    } else {
      size_t o = (size_t)(t * B_SZ + gbrow) * 2048 + (size_t)d * 1024 + gcol;
      out[o] = hnew;
      out[o + 67108864] = c_reg;
    }
  }
}

extern "C" void kernel_launch(void* const* d_in, const int* in_sizes, int n_in,
                              void* d_out, int out_size, void* d_ws, size_t ws_size,
                              hipStream_t stream) {
  (void)in_sizes; (void)n_in; (void)out_size; (void)ws_size;
  const int* tokens  = (const int*)d_in[0];
  const float* emb_w = (const float*)d_in[1];
  const float* emb_b = (const float*)d_in[2];

  char* ws = (char*)d_ws;
  short* embT   = (short*)(ws);               // 65,536,000 B
  short* Wbf    = (short*)(ws + 65536000);    // 33,554,432 B
  float* biasws = (float*)(ws + 99090432);    //     32,768 B
  short* hbf    = (short*)(ws + 99123200);    //    524,288 B (2 phase x 2 dir x 64x1024)
  unsigned* bar = (unsigned*)(ws + 99647488); //      1,024 B (flags)

  (void)hipMemsetAsync(ws + 99647488, 0, 1024, stream);

  k_embT<<<dim3(500, 16), 256, 0, stream>>>(emb_w, emb_b, embT);

  for (int d = 0; d < 2; ++d)
    for (int g = 0; g < 4; ++g) {
      const float* wsrc = (const float*)d_in[3 + d * 8 + g * 2];
      const float* bsrc = (const float*)d_in[4 + d * 8 + g * 2];
      k_cast<<<1024, 256, 0, stream>>>(wsrc, Wbf + (size_t)(d * 4 + g) * 1024 * 2048,
                                       1024 * 2048);
      k_copy<<<4, 256, 0, stream>>>(bsrc, biasws + (d * 4 + g) * 1024, 1024);
    }

  float* outp = (float*)d_out;
  void* kargs[] = {(void*)&tokens, (void*)&embT, (void*)&Wbf, (void*)&biasws,
                   (void*)&hbf, (void*)&bar, (void*)&outp};
  (void)hipLaunchCooperativeKernel((const void*)k_persist, dim3(256), dim3(512), kargs,
                                   0, stream);
}